// Round 12
// baseline (22982.434 us; speedup 1.0000x reference)
//
#include <hip/hip_runtime.h>

// FPS: x (B=64, N=65536, 3) f32 -> out (B, M=2048, 3) f32 gathered points.
// Verified fp semantics (round 3, absmax=0):
//   d = fma(dz,dz, round(dx*dx) + round(dy*dy)), min via fminf,
//   argmax tie-break = smallest global index.
// Round-12 = round-11 main kernel (byte-identical, 7.06ms) + a SYNC-ONLY
// PROBE kernel (4x2047 iterations of the full exchange skeleton, zero
// distance compute) to decompose the 3.45us/iter floor. Probe writes only
// to its own d_ws region; output correctness unchanged.

#define FPS_B 64
#define FPS_N 65536
#define FPS_M 2048
#define FPS_T 1024
#define FPS_Q 4                    // blocks per batch
#define FPS_GT (FPS_T * FPS_Q)     // 4096 threads per batch
#define FPS_PPT (FPS_N / FPS_GT)   // 16 points per thread
#define FPS_WAVES (FPS_T / 64)     // 16 waves per block

#define SLOT_U64 8                 // 64B global slot
#define BATCH_U64 (FPS_Q * 2 * SLOT_U64)   // 64 u64/batch
// d_ws layout (u64 units): [0,4096) main slots; [4096,8192) probe slots;
// [8192,8448) probe sink. memset covers all.
#define WS_PROBE_OFF 4096
#define WS_SINK_OFF  8192
#define WS_CLEAR_BYTES ((WS_SINK_OFF + 256) * 8)

#define PROBE_ITERS (4 * 2047)

#define AG_LOAD(p)    __hip_atomic_load((p), __ATOMIC_RELAXED, __HIP_MEMORY_SCOPE_AGENT)
#define AG_STORE(p,v) __hip_atomic_store((p), (v), __ATOMIC_RELAXED, __HIP_MEMORY_SCOPE_AGENT)

typedef float v2f __attribute__((ext_vector_type(2)));

static __device__ __forceinline__ v2f pk_add(v2f a, v2f b) {
    v2f d; asm("v_pk_add_f32 %0, %1, %2" : "=v"(d) : "v"(a), "v"(b)); return d;
}
static __device__ __forceinline__ v2f pk_mul(v2f a, v2f b) {
    v2f d; asm("v_pk_mul_f32 %0, %1, %2" : "=v"(d) : "v"(a), "v"(b)); return d;
}
static __device__ __forceinline__ v2f pk_fma(v2f a, v2f b, v2f c) {
    v2f d; asm("v_pk_fma_f32 %0, %1, %2, %3" : "=v"(d) : "v"(a), "v"(b), "v"(c)); return d;
}

#define PIN4(a,b,c,d) asm volatile("" : "+v"(a), "+v"(b), "+v"(c), "+v"(d))

// ---------------------------------------------------------------- main ----
__global__ __launch_bounds__(FPS_T, 4)
void fps_kernel(const float* __restrict__ x, float* __restrict__ out,
                unsigned long long* __restrict__ cand) {
    const int bid = blockIdx.x;
    const int c = bid & 7;
    const int v = bid >> 3;
    const int q = v & 3;           // block-in-batch
    const int b = (v >> 2) * 8 + c;

    const float* xb = x + (size_t)b * FPS_N * 3;
    float* ob = out + (size_t)b * FPS_M * 3;
    unsigned long long* cb = cand + (size_t)b * BATCH_U64;

    __shared__ char s_pad[96 * 1024];
    __shared__ unsigned long long s_entry[FPS_WAVES * 4];
    __shared__ float s_bc[3];

    const int t = threadIdx.x;
    const int wave = t >> 6;
    const int lane = t & 63;
    const int g = q * FPS_T + t;

    ((volatile char*)s_pad)[t * 96] = 0;

    v2f X0,X1,X2,X3,X4,X5,X6,X7;
    v2f Y0,Y1,Y2,Y3,Y4,Y5,Y6,Y7;
    v2f Z0,Z1,Z2,Z3,Z4,Z5,Z6,Z7;
    v2f M0,M1,M2,M3,M4,M5,M6,M7;
#define LOADP(j) do { \
        const int i0 = (2*(j)) * FPS_GT + g, i1 = i0 + FPS_GT; \
        X##j = (v2f){xb[3*i0+0], xb[3*i1+0]}; \
        Y##j = (v2f){xb[3*i0+1], xb[3*i1+1]}; \
        Z##j = (v2f){xb[3*i0+2], xb[3*i1+2]}; \
        M##j = (v2f){INFINITY, INFINITY}; } while (0)
    LOADP(0); LOADP(1); LOADP(2); LOADP(3);
    LOADP(4); LOADP(5); LOADP(6); LOADP(7);
#undef LOADP

    float px = xb[0], py = xb[1], pz = xb[2];
    if (q == 0 && t == 0) { ob[0] = px; ob[1] = py; ob[2] = pz; }

    long long budget = 1LL << 22;

    for (int s = 1; s < FPS_M; ++s) {
        PIN4(X0,X1,X2,X3); PIN4(X4,X5,X6,X7);
        PIN4(Y0,Y1,Y2,Y3); PIN4(Y4,Y5,Y6,Y7);
        PIN4(Z0,Z1,Z2,Z3); PIN4(Z4,Z5,Z6,Z7);

        const v2f npx = (v2f){-px, -px};
        const v2f npy = (v2f){-py, -py};
        const v2f npz = (v2f){-pz, -pz};

        float best = -INFINITY;
        int bk = 0;
#define STEPP(j) do { \
        const v2f dx = pk_add(X##j, npx); \
        const v2f dy = pk_add(Y##j, npy); \
        const v2f dz = pk_add(Z##j, npz); \
        const v2f sxy = pk_add(pk_mul(dx, dx), pk_mul(dy, dy)); \
        const v2f dd = pk_fma(dz, dz, sxy); \
        const float md0 = fminf(M##j.x, dd.x); \
        const float md1 = fminf(M##j.y, dd.y); \
        M##j.x = md0; M##j.y = md1; \
        if (md0 > best) { best = md0; bk = 2*(j); } \
        if (md1 > best) { best = md1; bk = 2*(j)+1; } } while (0)
        STEPP(0); STEPP(1); STEPP(2); STEPP(3);
        STEPP(4); STEPP(5); STEPP(6); STEPP(7);
#undef STEPP
        int besti = (bk << 12) | g;

#pragma unroll
        for (int m = 32; m >= 1; m >>= 1) {
            const float ov = __shfl_xor(best, m);
            const int   oi = __shfl_xor(besti, m);
            if (ov > best || (ov == best && oi < besti)) { best = ov; besti = oi; }
        }
        const int kw = besti >> 12;
        const int wl = besti & 63;
        float sx, sy, sz;
        switch (kw) {
            case  0: sx = X0.x; sy = Y0.x; sz = Z0.x; break;
            case  1: sx = X0.y; sy = Y0.y; sz = Z0.y; break;
            case  2: sx = X1.x; sy = Y1.x; sz = Z1.x; break;
            case  3: sx = X1.y; sy = Y1.y; sz = Z1.y; break;
            case  4: sx = X2.x; sy = Y2.x; sz = Z2.x; break;
            case  5: sx = X2.y; sy = Y2.y; sz = Z2.y; break;
            case  6: sx = X3.x; sy = Y3.x; sz = Z3.x; break;
            case  7: sx = X3.y; sy = Y3.y; sz = Z3.y; break;
            case  8: sx = X4.x; sy = Y4.x; sz = Z4.x; break;
            case  9: sx = X4.y; sy = Y4.y; sz = Z4.y; break;
            case 10: sx = X5.x; sy = Y5.x; sz = Z5.x; break;
            case 11: sx = X5.y; sy = Y5.y; sz = Z5.y; break;
            case 12: sx = X6.x; sy = Y6.x; sz = Z6.x; break;
            case 13: sx = X6.y; sy = Y6.y; sz = Z6.y; break;
            case 14: sx = X7.x; sy = Y7.x; sz = Z7.x; break;
            default: sx = X7.y; sy = Y7.y; sz = Z7.y; break;
        }
        const float wx = __shfl(sx, wl);
        const float wy = __shfl(sy, wl);
        const float wz = __shfl(sz, wl);

        if (lane < 4) {
            unsigned long long w;
            if (lane == 0)
                w = ((unsigned long long)__float_as_uint(best) << 32) |
                    ((unsigned long long)((~(unsigned)besti) & 0xFFFFu) << 11);
            else if (lane == 1) w = ((unsigned long long)__float_as_uint(wx) << 32);
            else if (lane == 2) w = ((unsigned long long)__float_as_uint(wy) << 32);
            else                w = ((unsigned long long)__float_as_uint(wz) << 32);
            s_entry[wave * 4 + lane] = w;
        }
        __syncthreads();

        const unsigned long long want = (unsigned long long)s;
        const int ring = s & 1;
        float npx2, npy2, npz2;

        if (wave == 0) {
            unsigned long long ew = s_entry[lane];
            unsigned long long u = ((lane & 3) == 0) ? ew : 0ull;
#pragma unroll
            for (int m = 4; m <= 32; m <<= 1) {
                const unsigned long long o = __shfl_xor(u, m);
                if (o > u) u = o;
            }
            const unsigned long long bw = __shfl(u, 0);
            const int widx = (int)((~(unsigned)(bw >> 11)) & 0xFFFFu);
            const int wv = (widx & 1023) >> 6;
            if (lane < 4) {
                const unsigned long long pw =
                    ((lane == 0) ? bw : s_entry[wv * 4 + lane]) | want;
                AG_STORE(&cb[(q * 2 + ring) * SLOT_U64 + lane], pw);
            }
            const int gl = lane & 15;
            unsigned long long pv = 0;
            bool ok = false;
            do {
                if (!ok) {
                    pv = AG_LOAD(&cb[((gl >> 2) * 2 + ring) * SLOT_U64 + (gl & 3)]);
                    ok = ((pv & 0x7FFull) == want);
                }
            } while (!__all(ok) && --budget > 0);
            const unsigned long long m0 = __shfl(pv, 0);
            const unsigned long long m1 = __shfl(pv, 4);
            const unsigned long long m2 = __shfl(pv, 8);
            const unsigned long long m3 = __shfl(pv, 12);
            const unsigned long long w01 = m0 > m1 ? m0 : m1;
            const unsigned long long w23 = m2 > m3 ? m2 : m3;
            const unsigned long long w = w01 > w23 ? w01 : w23;
            const int wb = (w == m0) ? 0 : ((w == m1) ? 1 : ((w == m2) ? 2 : 3));
            npx2 = __uint_as_float((unsigned)(__shfl(pv, wb * 4 + 1) >> 32));
            npy2 = __uint_as_float((unsigned)(__shfl(pv, wb * 4 + 2) >> 32));
            npz2 = __uint_as_float((unsigned)(__shfl(pv, wb * 4 + 3) >> 32));
            if (lane == 0) { s_bc[0] = npx2; s_bc[1] = npy2; s_bc[2] = npz2; }
            if (q == 0 && lane == 0) {
                ob[3 * s + 0] = npx2; ob[3 * s + 1] = npy2; ob[3 * s + 2] = npz2;
            }
        }
        __syncthreads();
        if (wave != 0) { npx2 = s_bc[0]; npy2 = s_bc[1]; npz2 = s_bc[2]; }
        px = npx2; py = npy2; pz = npz2;
    }
}

// --------------------------------------------------------------- probe ----
// Full exchange skeleton, zero distance compute. 32-bit stamps (seq can
// exceed 2048). Loop-carried via the exchanged winner word.
__global__ __launch_bounds__(FPS_T, 4)
void fps_sync_probe(unsigned long long* __restrict__ ws) {
    const int bid = blockIdx.x;
    const int c = bid & 7;
    const int v = bid >> 3;
    const int q = v & 3;
    const int b = (v >> 2) * 8 + c;
    unsigned long long* cb = ws + WS_PROBE_OFF + (size_t)b * BATCH_U64;

    __shared__ char s_pad[96 * 1024];
    __shared__ unsigned long long s_entry[FPS_WAVES * 4];
    __shared__ unsigned long long s_bc0;

    const int t = threadIdx.x;
    const int wave = t >> 6;
    const int lane = t & 63;

    ((volatile char*)s_pad)[t * 96] = 0;

    unsigned prev = 0x9E3779B9u ^ (unsigned)b;
    long long budget = 1LL << 26;

    for (int s = 1; s <= PROBE_ITERS; ++s) {
        // synthetic wave-best (few VALU ops; stands in for STEPP output)
        const unsigned h = (prev ^ ((unsigned)t * 2654435761u)) + (unsigned)s * 40503u;
        float best = __uint_as_float(h & 0x7FFFFFFFu);
        int besti = t;
        // wave argmax — identical shape to main
#pragma unroll
        for (int m = 32; m >= 1; m >>= 1) {
            const float ov = __shfl_xor(best, m);
            const int   oi = __shfl_xor(besti, m);
            if (ov > best || (ov == best && oi < besti)) { best = ov; besti = oi; }
        }
        const unsigned long long stamp = (unsigned long long)(unsigned)s;
        // deposit 4 words (payload<<32 | stamp), same as main
        if (lane < 4) {
            const unsigned pay = (lane == 0) ? __float_as_uint(best)
                                             : (__float_as_uint(best) ^ lane);
            s_entry[wave * 4 + lane] = ((unsigned long long)pay << 32) | stamp;
        }
        __syncthreads();           // barrier 1

        const int ring = s & 1;
        unsigned long long bc;

        if (wave == 0) {
            unsigned long long ew = s_entry[lane];
            unsigned long long u = ((lane & 3) == 0) ? ew : 0ull;
#pragma unroll
            for (int m = 4; m <= 32; m <<= 1) {
                const unsigned long long o = __shfl_xor(u, m);
                if (o > u) u = o;
            }
            const unsigned long long bw = __shfl(u, 0);
            const int wv = (int)((bw >> 38) & 15u);   // pseudo winner wave
            if (lane < 4) {
                const unsigned long long pw = (lane == 0) ? bw : s_entry[wv * 4 + lane];
                AG_STORE(&cb[(q * 2 + ring) * SLOT_U64 + lane], pw);
            }
            const int gl = lane & 15;
            unsigned long long pv = 0;
            bool ok = false;
            do {
                if (!ok) {
                    pv = AG_LOAD(&cb[((gl >> 2) * 2 + ring) * SLOT_U64 + (gl & 3)]);
                    ok = ((pv & 0xFFFFFFFFull) == stamp);
                }
            } while (!__all(ok) && --budget > 0);
            const unsigned long long m0 = __shfl(pv, 0);
            const unsigned long long m1 = __shfl(pv, 4);
            const unsigned long long m2 = __shfl(pv, 8);
            const unsigned long long m3 = __shfl(pv, 12);
            const unsigned long long w01 = m0 > m1 ? m0 : m1;
            const unsigned long long w23 = m2 > m3 ? m2 : m3;
            const unsigned long long w = w01 > w23 ? w01 : w23;
            const int wb = (w == m0) ? 0 : ((w == m1) ? 1 : ((w == m2) ? 2 : 3));
            bc = __shfl(pv, wb * 4 + 1);
            if (lane == 0) s_bc0 = bc;
        }
        __syncthreads();           // barrier 2
        if (wave != 0) bc = s_bc0;
        prev = (unsigned)(bc >> 32);   // loop-carried dependency
    }
    if (t == 0) ws[WS_SINK_OFF + bid] = (unsigned long long)prev;  // keep live
}

extern "C" void kernel_launch(void* const* d_in, const int* in_sizes, int n_in,
                              void* d_out, int out_size, void* d_ws, size_t ws_size,
                              hipStream_t stream) {
    const float* x = (const float*)d_in[0];
    float* out = (float*)d_out;
    unsigned long long* ws = (unsigned long long*)d_ws;
    (void)in_sizes; (void)n_in; (void)out_size; (void)ws_size;
    hipMemsetAsync(d_ws, 0, WS_CLEAR_BYTES, stream);
    fps_sync_probe<<<FPS_B * FPS_Q, FPS_T, 0, stream>>>(ws);
    fps_kernel<<<FPS_B * FPS_Q, FPS_T, 0, stream>>>(x, out, ws);
}

// Round 13
// 5967.958 us; speedup vs baseline: 3.8510x; 3.8510x over previous
//
#include <hip/hip_runtime.h>

// FPS: x (B=64, N=65536, 3) f32 -> out (B, M=2048, 3) f32 gathered points.
// Verified fp semantics (round 3, absmax=0):
//   d = fma(dz,dz, round(dx*dx) + round(dy*dy)), min via fminf,
//   argmax tie-break = smallest global index.
// Round-13 (probe r12: sync skeleton alone = 1.95us/iter, latency-chained):
//  - DPP+readlane reductions everywhere (VALU pipe ~8cy/hop) replacing
//    ds_bpermute shuffle chains (~40-50cy/hop): wave argmax, block combine,
//    final 4-slot combine + coord extract.
//  - tournament tree for thread-local 16-way best (depth 4 vs serial 32).
//  - bar2 removed: stamped 3xu64 LDS broadcast (r6-proven), bar1 kept.
//  - global ring/slot format byte-identical to r10 (proven correct).

#define FPS_B 64
#define FPS_N 65536
#define FPS_M 2048
#define FPS_T 1024
#define FPS_Q 4
#define FPS_GT (FPS_T * FPS_Q)     // 4096 threads per batch
#define FPS_PPT (FPS_N / FPS_GT)   // 16 points per thread
#define FPS_WAVES (FPS_T / 64)

#define SLOT_U64 8
#define BATCH_U64 (FPS_Q * 2 * SLOT_U64)

#define AG_LOAD(p)    __hip_atomic_load((p), __ATOMIC_RELAXED, __HIP_MEMORY_SCOPE_AGENT)
#define AG_STORE(p,v) __hip_atomic_store((p), (v), __ATOMIC_RELAXED, __HIP_MEMORY_SCOPE_AGENT)
#define WG_LOAD(p)    __hip_atomic_load((p), __ATOMIC_RELAXED, __HIP_MEMORY_SCOPE_WORKGROUP)
#define WG_STORE(p,v) __hip_atomic_store((p), (v), __ATOMIC_RELAXED, __HIP_MEMORY_SCOPE_WORKGROUP)

typedef float v2f __attribute__((ext_vector_type(2)));

static __device__ __forceinline__ v2f pk_add(v2f a, v2f b) {
    v2f d; asm("v_pk_add_f32 %0, %1, %2" : "=v"(d) : "v"(a), "v"(b)); return d;
}
static __device__ __forceinline__ v2f pk_mul(v2f a, v2f b) {
    v2f d; asm("v_pk_mul_f32 %0, %1, %2" : "=v"(d) : "v"(a), "v"(b)); return d;
}
static __device__ __forceinline__ v2f pk_fma(v2f a, v2f b, v2f c) {
    v2f d; asm("v_pk_fma_f32 %0, %1, %2, %3" : "=v"(d) : "v"(a), "v"(b), "v"(c)); return d;
}

#define PIN4(a,b,c,d) asm volatile("" : "+v"(a), "+v"(b), "+v"(c), "+v"(d))

// 6-step DPP max-reduce for nonneg u32 (identity 0); result in lane 63.
static __device__ __forceinline__ unsigned dppmax(unsigned x) {
    unsigned y;
    y = (unsigned)__builtin_amdgcn_update_dpp(0, (int)x, 0x111, 0xf, 0xf, true); x = x > y ? x : y;
    y = (unsigned)__builtin_amdgcn_update_dpp(0, (int)x, 0x112, 0xf, 0xf, true); x = x > y ? x : y;
    y = (unsigned)__builtin_amdgcn_update_dpp(0, (int)x, 0x114, 0xf, 0xf, true); x = x > y ? x : y;
    y = (unsigned)__builtin_amdgcn_update_dpp(0, (int)x, 0x118, 0xf, 0xf, true); x = x > y ? x : y;
    y = (unsigned)__builtin_amdgcn_update_dpp(0, (int)x, 0x142, 0xf, 0xf, true); x = x > y ? x : y;
    y = (unsigned)__builtin_amdgcn_update_dpp(0, (int)x, 0x143, 0xf, 0xf, true); x = x > y ? x : y;
    return x;
}

__global__ __launch_bounds__(FPS_T, 4)
void fps_kernel(const float* __restrict__ x, float* __restrict__ out,
                unsigned long long* __restrict__ cand) {
    const int bid = blockIdx.x;
    const int c = bid & 7;
    const int v = bid >> 3;
    const int q = v & 3;
    const int b = (v >> 2) * 8 + c;

    const float* xb = x + (size_t)b * FPS_N * 3;
    float* ob = out + (size_t)b * FPS_M * 3;
    unsigned long long* cb = cand + (size_t)b * BATCH_U64;

    __shared__ char s_pad[96 * 1024];        // 1 block/CU fence
    __shared__ unsigned long long s_vm[FPS_WAVES];   // val<<32 | besti
    __shared__ unsigned long long s_xy[FPS_WAVES];   // xbits<<32 | ybits
    __shared__ unsigned s_z[FPS_WAVES];
    __shared__ unsigned long long s_bc[3];           // coord<<32 | stamp

    const int t = threadIdx.x;
    const int wave = t >> 6;
    const int lane = t & 63;
    const int g = q * FPS_T + t;

    ((volatile char*)s_pad)[t * 96] = 0;
    if (t < 3) WG_STORE(&s_bc[t], 0ull);
    __syncthreads();   // one-time init barrier

    v2f X0,X1,X2,X3,X4,X5,X6,X7;
    v2f Y0,Y1,Y2,Y3,Y4,Y5,Y6,Y7;
    v2f Z0,Z1,Z2,Z3,Z4,Z5,Z6,Z7;
    v2f M0,M1,M2,M3,M4,M5,M6,M7;
#define LOADP(j) do { \
        const int i0 = (2*(j)) * FPS_GT + g, i1 = i0 + FPS_GT; \
        X##j = (v2f){xb[3*i0+0], xb[3*i1+0]}; \
        Y##j = (v2f){xb[3*i0+1], xb[3*i1+1]}; \
        Z##j = (v2f){xb[3*i0+2], xb[3*i1+2]}; \
        M##j = (v2f){INFINITY, INFINITY}; } while (0)
    LOADP(0); LOADP(1); LOADP(2); LOADP(3);
    LOADP(4); LOADP(5); LOADP(6); LOADP(7);
#undef LOADP

    float px = xb[0], py = xb[1], pz = xb[2];
    if (q == 0 && t == 0) { ob[0] = px; ob[1] = py; ob[2] = pz; }

    long long budget = 1LL << 22;

    for (int s = 1; s < FPS_M; ++s) {
        PIN4(X0,X1,X2,X3); PIN4(X4,X5,X6,X7);
        PIN4(Y0,Y1,Y2,Y3); PIN4(Y4,Y5,Y6,Y7);
        PIN4(Z0,Z1,Z2,Z3); PIN4(Z4,Z5,Z6,Z7);

        const v2f vnx = (v2f){-px, -px};
        const v2f vny = (v2f){-py, -py};
        const v2f vnz = (v2f){-pz, -pz};

#define STEPP(j) do { \
        const v2f dx = pk_add(X##j, vnx); \
        const v2f dy = pk_add(Y##j, vny); \
        const v2f dz = pk_add(Z##j, vnz); \
        const v2f sxy = pk_add(pk_mul(dx, dx), pk_mul(dy, dy)); \
        const v2f dd = pk_fma(dz, dz, sxy); \
        M##j.x = fminf(M##j.x, dd.x); \
        M##j.y = fminf(M##j.y, dd.y); } while (0)
        STEPP(0); STEPP(1); STEPP(2); STEPP(3);
        STEPP(4); STEPP(5); STEPP(6); STEPP(7);
#undef STEPP

        // tournament argmax over the 16 md values (ties keep left = first k)
#define PAIR(j) float p##j = (M##j.y > M##j.x) ? M##j.y : M##j.x; \
                int   e##j = (M##j.y > M##j.x) ? (2*(j)+1) : (2*(j))
        PAIR(0); PAIR(1); PAIR(2); PAIR(3);
        PAIR(4); PAIR(5); PAIR(6); PAIR(7);
#undef PAIR
        float a0 = (p1 > p0) ? p1 : p0;  int c0 = (p1 > p0) ? e1 : e0;
        float a1 = (p3 > p2) ? p3 : p2;  int c1 = (p3 > p2) ? e3 : e2;
        float a2 = (p5 > p4) ? p5 : p4;  int c2 = (p5 > p4) ? e5 : e4;
        float a3 = (p7 > p6) ? p7 : p6;  int c3 = (p7 > p6) ? e7 : e6;
        float d0 = (a1 > a0) ? a1 : a0;  int f0 = (a1 > a0) ? c1 : c0;
        float d1 = (a3 > a2) ? a3 : a2;  int f1 = (a3 > a2) ? c3 : c2;
        float best = (d1 > d0) ? d1 : d0;
        int bk = (d1 > d0) ? f1 : f0;
        const int besti = (bk << 12) | g;

        // wave argmax: DPP umax on val bits (f32>=0 monotone), then keyed min-idx
        const unsigned vb = __float_as_uint(best);
        const unsigned mv = (unsigned)__builtin_amdgcn_readlane((int)dppmax(vb), 63);
        const unsigned key = (vb == mv)
            ? ((((unsigned)(~besti) & 0xFFFFu) << 5) | 1u) : 0u;
        const unsigned mk = (unsigned)__builtin_amdgcn_readlane((int)dppmax(key), 63);
        const int wbesti = (int)(~(mk >> 5) & 0xFFFFu);

        // winner coords: kw uniform -> switch; owner lane via readlane
        const int kw = wbesti >> 12;
        const int wl = wbesti & 63;
        float sx, sy, sz;
        switch (kw) {
            case  0: sx = X0.x; sy = Y0.x; sz = Z0.x; break;
            case  1: sx = X0.y; sy = Y0.y; sz = Z0.y; break;
            case  2: sx = X1.x; sy = Y1.x; sz = Z1.x; break;
            case  3: sx = X1.y; sy = Y1.y; sz = Z1.y; break;
            case  4: sx = X2.x; sy = Y2.x; sz = Z2.x; break;
            case  5: sx = X2.y; sy = Y2.y; sz = Z2.y; break;
            case  6: sx = X3.x; sy = Y3.x; sz = Z3.x; break;
            case  7: sx = X3.y; sy = Y3.y; sz = Z3.y; break;
            case  8: sx = X4.x; sy = Y4.x; sz = Z4.x; break;
            case  9: sx = X4.y; sy = Y4.y; sz = Z4.y; break;
            case 10: sx = X5.x; sy = Y5.x; sz = Z5.x; break;
            case 11: sx = X5.y; sy = Y5.y; sz = Z5.y; break;
            case 12: sx = X6.x; sy = Y6.x; sz = Z6.x; break;
            case 13: sx = X6.y; sy = Y6.y; sz = Z6.y; break;
            case 14: sx = X7.x; sy = Y7.x; sz = Z7.x; break;
            default: sx = X7.y; sy = Y7.y; sz = Z7.y; break;
        }
        const unsigned wxb = (unsigned)__builtin_amdgcn_readlane((int)__float_as_uint(sx), wl);
        const unsigned wyb = (unsigned)__builtin_amdgcn_readlane((int)__float_as_uint(sy), wl);
        const unsigned wzb = (unsigned)__builtin_amdgcn_readlane((int)__float_as_uint(sz), wl);

        // deposit wave winner (lane 0, 3 stores; all values uniform)
        if (lane == 0) {
            s_vm[wave] = ((unsigned long long)mv << 32) | (unsigned)wbesti;
            s_xy[wave] = ((unsigned long long)wxb << 32) | wyb;
            s_z[wave]  = wzb;
        }
        __syncthreads();   // bar1: deposits visible to wave0

        const unsigned long long want = (unsigned long long)s;
        const int ring = s & 1;

        if (wave == 0) {
            // gather 16 entries (broadcast reads), DPP combine
            const unsigned long long vm = s_vm[lane & 15];
            const unsigned ev = (lane < 16) ? (unsigned)(vm >> 32) : 0u;
            const unsigned em = (unsigned)vm;   // wave-winner besti
            const unsigned mv2 = (unsigned)__builtin_amdgcn_readlane((int)dppmax(ev), 63);
            const unsigned key2 = (lane < 16 && ev == mv2)
                ? ((((~em) & 0xFFFFu) << 5) | (unsigned)(lane + 1)) : 0u;
            const unsigned mk2 = (unsigned)__builtin_amdgcn_readlane((int)dppmax(key2), 63);
            const int wE = (int)(mk2 & 0x1Fu) - 1;           // winner wave entry
            const unsigned nidx = (mk2 >> 5) & 0xFFFFu;      // ~besti of winner
            const unsigned long long cxy = s_xy[wE];
            const unsigned czb = s_z[wE];

            // publish block winner (lanes 0-3, slot format == r10)
            if (lane < 4) {
                unsigned long long w;
                if (lane == 0)
                    w = (((unsigned long long)mv2) << 32) |
                        (((unsigned long long)nidx) << 11) | want;
                else if (lane == 1) w = ((unsigned long long)(unsigned)(cxy >> 32) << 32) | want;
                else if (lane == 2) w = ((unsigned long long)(unsigned)cxy << 32) | want;
                else                w = ((unsigned long long)czb << 32) | want;
                AG_STORE(&cb[(q * 2 + ring) * SLOT_U64 + lane], w);
            }
            // merged poll: lane -> word (lane&15)&3 of slot (lane&15)>>2
            const int gl = lane & 15;
            unsigned long long pv = 0;
            bool ok = false;
            do {
                if (!ok) {
                    pv = AG_LOAD(&cb[((gl >> 2) * 2 + ring) * SLOT_U64 + (gl & 3)]);
                    ok = ((pv & 0x7FFull) == want);
                }
            } while (!__all(ok) && --budget > 0);

            // combine 4 slot word0s via DPP, extract coords via readlane
            const unsigned hi = (unsigned)(pv >> 32);
            const bool w0lane = ((lane & 3) == 0) && (lane < 16);
            const unsigned pvv = w0lane ? hi : 0u;
            const unsigned mv3 = (unsigned)__builtin_amdgcn_readlane((int)dppmax(pvv), 63);
            const unsigned key3 = (w0lane && pvv == mv3)
                ? (((((unsigned)(pv >> 11)) & 0xFFFFu) << 7) | (unsigned)((lane >> 2) + 1)) : 0u;
            const unsigned mk3 = (unsigned)__builtin_amdgcn_readlane((int)dppmax(key3), 63);
            const int wb = (int)(mk3 & 0x7Fu) - 1;
            const unsigned xw = (unsigned)__builtin_amdgcn_readlane((int)hi, wb * 4 + 1);
            const unsigned yw = (unsigned)__builtin_amdgcn_readlane((int)hi, wb * 4 + 2);
            const unsigned zw = (unsigned)__builtin_amdgcn_readlane((int)hi, wb * 4 + 3);

            if (lane == 0) {
                WG_STORE(&s_bc[0], ((unsigned long long)xw << 32) | want);
                WG_STORE(&s_bc[1], ((unsigned long long)yw << 32) | want);
                WG_STORE(&s_bc[2], ((unsigned long long)zw << 32) | want);
                if (q == 0) {
                    ob[3 * s + 0] = __uint_as_float(xw);
                    ob[3 * s + 1] = __uint_as_float(yw);
                    ob[3 * s + 2] = __uint_as_float(zw);
                }
            }
            px = __uint_as_float(xw);
            py = __uint_as_float(yw);
            pz = __uint_as_float(zw);
        } else {
            // stamped LDS spin replaces bar2 (r6-proven pattern)
            unsigned long long b0, b1, b2;
            do { b0 = WG_LOAD(&s_bc[0]); } while ((b0 & 0x7FFull) != want && --budget > 0);
            do { b1 = WG_LOAD(&s_bc[1]); } while ((b1 & 0x7FFull) != want && --budget > 0);
            do { b2 = WG_LOAD(&s_bc[2]); } while ((b2 & 0x7FFull) != want && --budget > 0);
            px = __uint_as_float((unsigned)(b0 >> 32));
            py = __uint_as_float((unsigned)(b1 >> 32));
            pz = __uint_as_float((unsigned)(b2 >> 32));
        }
    }
}

extern "C" void kernel_launch(void* const* d_in, const int* in_sizes, int n_in,
                              void* d_out, int out_size, void* d_ws, size_t ws_size,
                              hipStream_t stream) {
    const float* x = (const float*)d_in[0];
    float* out = (float*)d_out;
    unsigned long long* cand = (unsigned long long*)d_ws;
    (void)in_sizes; (void)n_in; (void)out_size; (void)ws_size;
    hipMemsetAsync(d_ws, 0, FPS_B * BATCH_U64 * sizeof(unsigned long long), stream);
    fps_kernel<<<FPS_B * FPS_Q, FPS_T, 0, stream>>>(x, out, cand);
}